// Round 5
// baseline (1395.373 us; speedup 1.0000x reference)
//
#include <hip/hip_runtime.h>
#include <hip/hip_bf16.h>
#include <math.h>

#define F_IN   2000
#define HID    16
#define HEADS  4
#define CPH    16
#define HC     64
#define NCLS   3

// --- TEMPORARY instrumentation: in-kernel idempotent repeats so the big
// --- kernels exceed the harness-fill duration band and surface in the
// --- rocprof top-5 with their own counters. Revert to 1 next round.
#define GEMM_REPS 4
#define GCN_REPS  8
#define GAT_REPS  8

__device__ __forceinline__ float lrelu(float x){ return x > 0.f ? x : 0.2f*x; }

__device__ __forceinline__ float comp4(const float4& v, int k){
  return k==0 ? v.x : k==1 ? v.y : k==2 ? v.z : v.w;
}

__device__ __forceinline__ float sel4(float a, float b, float c, float d, int h){
  float lo = (h&1) ? b : a;
  float hi = (h&1) ? d : c;
  return (h&2) ? hi : lo;
}

// ---------------------------------------------------------------------------
// K0: zero deg
// ---------------------------------------------------------------------------
__global__ void k_zero(int* __restrict__ deg, int n) {
  int i = blockIdx.x * 256 + threadIdx.x;
  if (i < n) deg[i] = 0;
}

// ---------------------------------------------------------------------------
// K1: h0 = x @ W1   [n,2000] @ [2000,16] -> [n,16]   (structure as R4)
// ---------------------------------------------------------------------------
__global__ __launch_bounds__(256) void k_gemm1(const float* __restrict__ x,
                                               const float* __restrict__ W1,
                                               float* __restrict__ h0, int n) {
  __shared__ float w1s[8192];            // 512 rows x 16 floats (swizzled) = 32 KB
  const int t    = threadIdx.x;
  const int lane = t & 63;
  const int wid  = t >> 6;               // 0..3
  const int rowbase = blockIdx.x * 16 + wid * 4;

  for (int rep = 0; rep < GEMM_REPS; ++rep) {
    float acc[64];                         // acc[r*16 + c]
    #pragma unroll
    for (int v = 0; v < 64; ++v) acc[v] = 0.f;

    for (int phase = 0; phase < 4; ++phase) {
      const int kbase = phase * 500;
      __syncthreads();
      #pragma unroll
      for (int k = 0; k < 8; ++k) {
        const int slotbase = (wid * 8 + k) * 64;      // wave-uniform
        const int slot = slotbase + lane;
        const int row_slot = slot >> 2;
        const int r = row_slot ^ ((row_slot >> 4) & 1);
        const int q = (slot & 3) ^ ((row_slot >> 2) & 3);
        int rg = kbase + r;
        if (rg > 1999) rg = 1999;                     // clamp; junk slots unread
        __builtin_amdgcn_global_load_lds(
            (const __attribute__((address_space(1))) void*)(W1 + (size_t)rg * 16 + q * 4),
            (__attribute__((address_space(3))) void*)(w1s + (size_t)slotbase * 4),
            16, 0, 0);
      }
      __syncthreads();                                // drains vmcnt -> LDS ready

      #pragma unroll
      for (int i = 0; i < 2; ++i) {
        int f4l = i * 64 + lane;            // local float4-of-K index, <125 valid
        if (f4l < 125) {
          float4 xv[4];
          #pragma unroll
          for (int r = 0; r < 4; ++r) {
            int row = rowbase + r;
            xv[r] = (row < n)
                ? *reinterpret_cast<const float4*>(
                      x + (size_t)row * F_IN + kbase + f4l * 4)
                : make_float4(0.f, 0.f, 0.f, 0.f);
          }
          const int qx = f4l & 3;
          const int xb = (f4l >> 2) & 1;
          #pragma unroll
          for (int kk = 0; kk < 4; ++kk) {
            const int rs = (4 * f4l + kk) ^ xb;       // swizzled row slot
            const float* rowp = w1s + rs * 16;
            float xk0 = comp4(xv[0], kk), xk1 = comp4(xv[1], kk);
            float xk2 = comp4(xv[2], kk), xk3 = comp4(xv[3], kk);
            #pragma unroll
            for (int q = 0; q < 4; ++q) {
              float4 w4 = *reinterpret_cast<const float4*>(rowp + ((q ^ qx) << 2));
              acc[0*16+4*q+0] += xk0 * w4.x; acc[0*16+4*q+1] += xk0 * w4.y;
              acc[0*16+4*q+2] += xk0 * w4.z; acc[0*16+4*q+3] += xk0 * w4.w;
              acc[1*16+4*q+0] += xk1 * w4.x; acc[1*16+4*q+1] += xk1 * w4.y;
              acc[1*16+4*q+2] += xk1 * w4.z; acc[1*16+4*q+3] += xk1 * w4.w;
              acc[2*16+4*q+0] += xk2 * w4.x; acc[2*16+4*q+1] += xk2 * w4.y;
              acc[2*16+4*q+2] += xk2 * w4.z; acc[2*16+4*q+3] += xk2 * w4.w;
              acc[3*16+4*q+0] += xk3 * w4.x; acc[3*16+4*q+1] += xk3 * w4.y;
              acc[3*16+4*q+2] += xk3 * w4.z; acc[3*16+4*q+3] += xk3 * w4.w;
            }
          }
        }
      }
    }

    // reduce-scatter across 64 lanes
    #pragma unroll
    for (int b = 32; b >= 1; b >>= 1) {
      bool hi = (lane & b) != 0;
      #pragma unroll
      for (int j = 0; j < b; ++j) {
        float send = hi ? acc[j] : acc[b + j];
        float recv = __shfl_xor(send, b);
        acc[j] = (hi ? acc[b + j] : acc[j]) + recv;
      }
    }
    int r = lane >> 4, c = lane & 15;
    int row = rowbase + r;
    if (row < n) h0[(size_t)row * 16 + c] = acc[0];
  }
}

// ---------------------------------------------------------------------------
// K2: in-degree count
// ---------------------------------------------------------------------------
__global__ void k_deg(const int* __restrict__ edst, int* __restrict__ deg, int e) {
  int i = blockIdx.x * 256 + threadIdx.x;
  if (i < e) atomicAdd(&deg[edst[i]], 1);
}

// ---------------------------------------------------------------------------
// K3a/b/c: exclusive prefix scan of deg -> rowptr (+cursor); dinv = rsqrt(deg+1)
// ---------------------------------------------------------------------------
__global__ void k_scan_a(const int* __restrict__ deg, int* __restrict__ bsum, int n) {
  __shared__ int s[256];
  int i = blockIdx.x * 256 + threadIdx.x;
  s[threadIdx.x] = (i < n) ? deg[i] : 0;
  __syncthreads();
  for (int off = 128; off > 0; off >>= 1) {
    if (threadIdx.x < off) s[threadIdx.x] += s[threadIdx.x + off];
    __syncthreads();
  }
  if (threadIdx.x == 0) bsum[blockIdx.x] = s[0];
}

__global__ void k_scan_b(int* __restrict__ bsum, int nb) {
  int lane = threadIdx.x;   // 64 threads
  int carry = 0;
  for (int base = 0; base < nb; base += 64) {
    int idx = base + lane;
    int orig = (idx < nb) ? bsum[idx] : 0;
    int v = orig;
    #pragma unroll
    for (int off = 1; off < 64; off <<= 1) {
      int tv = __shfl_up(v, off);
      if (lane >= off) v += tv;
    }
    if (idx < nb) bsum[idx] = carry + v - orig;   // exclusive
    carry += __shfl(v, 63);
  }
}

__global__ void k_scan_c(const int* __restrict__ deg, const int* __restrict__ bsum,
                         int* __restrict__ rowptr, int* __restrict__ cursor,
                         float* __restrict__ dinv, int n) {
  __shared__ int s[256];
  int i = blockIdx.x * 256 + threadIdx.x;
  int v = (i < n) ? deg[i] : 0;
  s[threadIdx.x] = v;
  __syncthreads();
  for (int off = 1; off < 256; off <<= 1) {
    int tv = (threadIdx.x >= off) ? s[threadIdx.x - off] : 0;
    __syncthreads();
    s[threadIdx.x] += tv;
    __syncthreads();
  }
  int excl = s[threadIdx.x] - v + bsum[blockIdx.x];
  if (i < n) {
    rowptr[i] = excl;
    cursor[i] = excl;
    dinv[i] = rsqrtf((float)(v + 1));
    if (i == n - 1) rowptr[n] = excl + v;
  }
}

// ---------------------------------------------------------------------------
// K4: scatter edges into CSR
// ---------------------------------------------------------------------------
__global__ void k_scatter(const int* __restrict__ esrc, const int* __restrict__ edst,
                          int* __restrict__ cursor, int* __restrict__ csr, int e) {
  int i = blockIdx.x * 256 + threadIdx.x;
  if (i < e) {
    int d = edst[i];
    int pos = atomicAdd(&cursor[d], 1);
    csr[pos] = esrc[i];
  }
}

// ---------------------------------------------------------------------------
// K5: per-dst GCN aggregate + bias + relu, then g = h@Wg, a_s/a_d dots.
// ---------------------------------------------------------------------------
__global__ __launch_bounds__(256) void k_gcn(
    const float* __restrict__ h0, const int* __restrict__ rowptr,
    const int* __restrict__ csr, const float* __restrict__ dinv,
    const float* __restrict__ b1, const float* __restrict__ Wg,
    const float* __restrict__ atts, const float* __restrict__ attd,
    float* __restrict__ g, float* __restrict__ a_s, float* __restrict__ a_d, int n) {
  __shared__ float wgs[HID * HC];
  __shared__ float ats[HC], atd[HC];
  int t = threadIdx.x;
  for (int i = t; i < HID * HC; i += 256) wgs[i] = Wg[i];
  if (t < HC) { ats[t] = atts[t]; atd[t] = attd[t]; }
  __syncthreads();

  int lane = t & 63, w = t >> 6;
  int dst = blockIdx.x * 4 + w;
  if (dst >= n) return;
  int j = lane >> 4, c = lane & 15;
  int start = rowptr[dst], end = rowptr[dst + 1];
  float dd = dinv[dst];

  for (int rep = 0; rep < GCN_REPS; ++rep) {
    float acc = 0.f;
    for (int idx = start + j; idx < end; idx += 4) {
      int src = csr[idx];
      acc += h0[(size_t)src * 16 + c] * dinv[src];
    }
    acc += __shfl_xor(acc, 16);
    acc += __shfl_xor(acc, 32);
    acc = acc * dd + h0[(size_t)dst * 16 + c] * dd * dd;   // + self loop
    float hv = fmaxf(acc + b1[c], 0.f);                     // bias + relu

    float go = 0.f;
    #pragma unroll
    for (int k = 0; k < 16; ++k) {
      float hk = __shfl(hv, k);
      go += hk * wgs[k * HC + lane];
    }
    g[(size_t)dst * HC + lane] = go;

    float asv = go * ats[lane], adv = go * atd[lane];
    #pragma unroll
    for (int m = 1; m < 16; m <<= 1) {
      asv += __shfl_xor(asv, m);
      adv += __shfl_xor(adv, m);
    }
    if (c == 0) {
      a_s[(size_t)dst * 4 + j] = asv;
      a_d[(size_t)dst * 4 + j] = adv;
    }
  }
}

// ---------------------------------------------------------------------------
// K6: per-dst GAT softmax + aggregate + bias + classifier + log_softmax.
// ---------------------------------------------------------------------------
__global__ __launch_bounds__(256) void k_gat(
    const float* __restrict__ g, const int* __restrict__ rowptr,
    const int* __restrict__ csr, const float* __restrict__ a_s,
    const float* __restrict__ a_d, const float* __restrict__ bg,
    const float* __restrict__ Wo, const float* __restrict__ bo,
    float* __restrict__ out, int n) {
  __shared__ float wos[HC * NCLS];
  __shared__ float bgs[HC];
  __shared__ float bos[NCLS];
  int t = threadIdx.x;
  if (t < HC * NCLS) wos[t] = Wo[t];
  if (t < HC) bgs[t] = bg[t];
  if (t < NCLS) bos[t] = bo[t];
  __syncthreads();

  int lane = t & 63, w = t >> 6;
  int dst = blockIdx.x * 4 + w;
  if (dst >= n) return;
  int start = rowptr[dst], end = rowptr[dst + 1];

  for (int rep = 0; rep < GAT_REPS; ++rep) {
    float4 ad4 = *reinterpret_cast<const float4*>(a_d + (size_t)dst * 4);
    float4 asS = *reinterpret_cast<const float4*>(a_s + (size_t)dst * 4);

    // ---- pass 1: per-head max over incoming edges + self ----
    float m0 = -1e30f, m1 = -1e30f, m2 = -1e30f, m3 = -1e30f;
    for (int idx = start + lane; idx < end; idx += 64) {
      int src = csr[idx];
      float4 s4 = *reinterpret_cast<const float4*>(a_s + (size_t)src * 4);
      m0 = fmaxf(m0, lrelu(s4.x + ad4.x));
      m1 = fmaxf(m1, lrelu(s4.y + ad4.y));
      m2 = fmaxf(m2, lrelu(s4.z + ad4.z));
      m3 = fmaxf(m3, lrelu(s4.w + ad4.w));
    }
    #pragma unroll
    for (int msk = 32; msk >= 1; msk >>= 1) {
      m0 = fmaxf(m0, __shfl_xor(m0, msk));
      m1 = fmaxf(m1, __shfl_xor(m1, msk));
      m2 = fmaxf(m2, __shfl_xor(m2, msk));
      m3 = fmaxf(m3, __shfl_xor(m3, msk));
    }
    float es0 = lrelu(asS.x + ad4.x), es1 = lrelu(asS.y + ad4.y);
    float es2 = lrelu(asS.z + ad4.z), es3 = lrelu(asS.w + ad4.w);
    m0 = fmaxf(m0, es0); m1 = fmaxf(m1, es1);
    m2 = fmaxf(m2, es2); m3 = fmaxf(m3, es3);

    // ---- pass 2: exp / weighted aggregate ----
    int j = lane >> 4, c = lane & 15, h = c >> 2;
    float mh  = sel4(m0, m1, m2, m3, h);
    float adh = sel4(ad4.x, ad4.y, ad4.z, ad4.w, h);
    float esh = sel4(es0, es1, es2, es3, h);

    float a0 = 0.f, a1 = 0.f, a2 = 0.f, a3 = 0.f, den = 0.f;
    for (int idx = start + j; idx < end; idx += 4) {
      int src = csr[idx];
      float e = lrelu(a_s[(size_t)src * 4 + h] + adh);
      float ex = __expf(e - mh);
      float4 gv = *reinterpret_cast<const float4*>(g + (size_t)src * HC + c * 4);
      a0 += ex * gv.x; a1 += ex * gv.y; a2 += ex * gv.z; a3 += ex * gv.w;
      den += ex;
    }
    if (j == 0) {
      float ex = __expf(esh - mh);
      float4 gv = *reinterpret_cast<const float4*>(g + (size_t)dst * HC + c * 4);
      a0 += ex * gv.x; a1 += ex * gv.y; a2 += ex * gv.z; a3 += ex * gv.w;
      den += ex;
    }
    a0 += __shfl_xor(a0, 16); a0 += __shfl_xor(a0, 32);
    a1 += __shfl_xor(a1, 16); a1 += __shfl_xor(a1, 32);
    a2 += __shfl_xor(a2, 16); a2 += __shfl_xor(a2, 32);
    a3 += __shfl_xor(a3, 16); a3 += __shfl_xor(a3, 32);
    den += __shfl_xor(den, 16); den += __shfl_xor(den, 32);
    den += 1e-16f;

    float o0 = a0 / den + bgs[c * 4 + 0];
    float o1 = a1 / den + bgs[c * 4 + 1];
    float o2 = a2 / den + bgs[c * 4 + 2];
    float o3 = a3 / den + bgs[c * 4 + 3];

    float p0 = 0.f, p1 = 0.f, p2 = 0.f;
    {
      int ch = c * 4;
      p0 += o0 * wos[(ch+0)*NCLS+0] + o1 * wos[(ch+1)*NCLS+0] + o2 * wos[(ch+2)*NCLS+0] + o3 * wos[(ch+3)*NCLS+0];
      p1 += o0 * wos[(ch+0)*NCLS+1] + o1 * wos[(ch+1)*NCLS+1] + o2 * wos[(ch+2)*NCLS+1] + o3 * wos[(ch+3)*NCLS+1];
      p2 += o0 * wos[(ch+0)*NCLS+2] + o1 * wos[(ch+1)*NCLS+2] + o2 * wos[(ch+2)*NCLS+2] + o3 * wos[(ch+3)*NCLS+2];
    }
    #pragma unroll
    for (int msk = 1; msk < 16; msk <<= 1) {
      p0 += __shfl_xor(p0, msk);
      p1 += __shfl_xor(p1, msk);
      p2 += __shfl_xor(p2, msk);
    }
    p0 += bos[0]; p1 += bos[1]; p2 += bos[2];
    float mx = fmaxf(p0, fmaxf(p1, p2));
    float ls = mx + logf(__expf(p0 - mx) + __expf(p1 - mx) + __expf(p2 - mx));
    if (lane == 0) {
      out[(size_t)dst * 3 + 0] = p0 - ls;
      out[(size_t)dst * 3 + 1] = p1 - ls;
      out[(size_t)dst * 3 + 2] = p2 - ls;
    }
  }
}

// ---------------------------------------------------------------------------
extern "C" void kernel_launch(void* const* d_in, const int* in_sizes, int n_in,
                              void* d_out, int out_size, void* d_ws, size_t ws_size,
                              hipStream_t stream) {
  const float* x    = (const float*)d_in[0];
  const int*   ei   = (const int*)  d_in[1];
  const float* W1   = (const float*)d_in[2];
  const float* b1   = (const float*)d_in[3];
  const float* Wg   = (const float*)d_in[4];
  const float* atts = (const float*)d_in[5];
  const float* attd = (const float*)d_in[6];
  const float* bg   = (const float*)d_in[7];
  const float* Wo   = (const float*)d_in[8];
  const float* bo   = (const float*)d_in[9];
  float* out = (float*)d_out;

  const int n = in_sizes[0] / F_IN;
  const int e = in_sizes[1] / 2;
  const int* esrc = ei;
  const int* edst = ei + e;

  char* p = (char*)d_ws;
  auto alloc = [&](size_t bytes) { char* r = p; p += (bytes + 255) & ~(size_t)255; return r; };
  float* h0     = (float*)alloc((size_t)n * 16 * 4);
  int*   deg    = (int*)  alloc((size_t)n * 4);
  int*   cursor = (int*)  alloc((size_t)n * 4);
  float* dinv   = (float*)alloc((size_t)n * 4);
  int*   rowptr = (int*)  alloc((size_t)(n + 1) * 4);
  int*   bsum   = (int*)  alloc(4096);
  int*   csr    = (int*)  alloc((size_t)e * 4);
  float* gbuf   = (float*)alloc((size_t)n * HC * 4);
  float* as_    = (float*)alloc((size_t)n * 4 * 4);
  float* ad_    = (float*)alloc((size_t)n * 4 * 4);

  int nzb = (n + 255) / 256;
  k_zero<<<nzb, 256, 0, stream>>>(deg, n);

  k_gemm1<<<(n + 15) / 16, 256, 0, stream>>>(x, W1, h0, n);

  k_deg<<<(e + 255) / 256, 256, 0, stream>>>(edst, deg, e);

  int nb = (n + 255) / 256;
  k_scan_a<<<nb, 256, 0, stream>>>(deg, bsum, n);
  k_scan_b<<<1, 64, 0, stream>>>(bsum, nb);
  k_scan_c<<<nb, 256, 0, stream>>>(deg, bsum, rowptr, cursor, dinv, n);

  k_scatter<<<(e + 255) / 256, 256, 0, stream>>>(esrc, edst, cursor, csr, e);

  k_gcn<<<(n + 3) / 4, 256, 0, stream>>>(h0, rowptr, csr, dinv, b1, Wg, atts, attd,
                                         gbuf, as_, ad_, n);

  k_gat<<<(n + 3) / 4, 256, 0, stream>>>(gbuf, rowptr, csr, as_, ad_, bg, Wo, bo,
                                         out, n);
}

// Round 6
// 981.113 us; speedup vs baseline: 1.4222x; 1.4222x over previous
//
#include <hip/hip_runtime.h>
#include <hip/hip_bf16.h>
#include <math.h>

#define F_IN   2000
#define HID    16
#define HEADS  4
#define CPH    16
#define HC     64
#define NCLS   3

__device__ __forceinline__ float lrelu(float x){ return x > 0.f ? x : 0.2f*x; }

__device__ __forceinline__ float comp4(const float4& v, int k){
  return k==0 ? v.x : k==1 ? v.y : k==2 ? v.z : v.w;
}

__device__ __forceinline__ float bf2f(unsigned short u){
  return __uint_as_float(((unsigned)u) << 16);
}

// ---------------------------------------------------------------------------
// K0: zero deg
// ---------------------------------------------------------------------------
__global__ void k_zero(int* __restrict__ deg, int n) {
  int i = blockIdx.x * 256 + threadIdx.x;
  if (i < n) deg[i] = 0;
}

// ---------------------------------------------------------------------------
// K1: h0 = x @ W1 -> bf16   [n,2000]@[2000,16]
// 256 thr = 4 waves x 8 rows (block = 32 rows). Flat 8-chunk pipeline
// (chunk = phase*2+i, phase = 500 K-rows in 32KB LDS, swizzled via
// global_load_lds with pre-swizzled source). Next chunk's 8 x-float4 loads
// are issued before the current chunk's 512-FMA block -> HBM latency hidden.
// W1 LDS traffic halved vs 4-row version (128KB amortized over 8 rows).
// ---------------------------------------------------------------------------
__global__ __launch_bounds__(256, 2) void k_gemm1(const float* __restrict__ x,
                                                  const float* __restrict__ W1,
                                                  __hip_bfloat16* __restrict__ h0b,
                                                  int n) {
  __shared__ float w1s[8192];            // 512 rows x 16 floats (swizzled)
  const int t    = threadIdx.x;
  const int lane = t & 63;
  const int wid  = t >> 6;               // 0..3
  const int rowbase = blockIdx.x * 32 + wid * 8;

  float acc[128];                        // acc[r*16+c], r=0..7
  #pragma unroll
  for (int v = 0; v < 128; ++v) acc[v] = 0.f;

  float4 xc[8], xn[8];

  auto stage = [&](int phase) {
    const int kbase = phase * 500;
    #pragma unroll
    for (int k = 0; k < 8; ++k) {
      const int slotbase = (wid * 8 + k) * 64;      // wave-uniform
      const int slot = slotbase + lane;
      const int row_slot = slot >> 2;
      const int r = row_slot ^ ((row_slot >> 4) & 1);
      const int q = (slot & 3) ^ ((row_slot >> 2) & 3);
      int rg = kbase + r;
      if (rg > 1999) rg = 1999;                     // clamp; junk rows unread
      __builtin_amdgcn_global_load_lds(
          (const __attribute__((address_space(1))) void*)(W1 + (size_t)rg * 16 + q * 4),
          (__attribute__((address_space(3))) void*)(w1s + (size_t)slotbase * 4),
          16, 0, 0);
    }
  };

  auto loadx = [&](float4* xv, int c) {
    const int i = c & 1;
    const int f4l = i * 64 + lane;
    const bool kv = (f4l < 125);
    const int kb = (c >> 1) * 500 + f4l * 4;
    #pragma unroll
    for (int r = 0; r < 8; ++r) {
      int row = rowbase + r;
      xv[r] = (kv && row < n)
          ? *reinterpret_cast<const float4*>(x + (size_t)row * F_IN + kb)
          : make_float4(0.f, 0.f, 0.f, 0.f);
    }
  };

  auto compute = [&](const float4* xv, int c) {
    const int i = c & 1;
    const int f4l = i * 64 + lane;
    const int qx = f4l & 3;
    const int xb = (f4l >> 2) & 1;
    #pragma unroll
    for (int kk = 0; kk < 4; ++kk) {
      const int rs = (4 * f4l + kk) ^ xb;           // swizzled row slot
      const float* rowp = w1s + rs * 16;
      float xk[8];
      #pragma unroll
      for (int r = 0; r < 8; ++r) xk[r] = comp4(xv[r], kk);
      #pragma unroll
      for (int q = 0; q < 4; ++q) {
        float4 w4 = *reinterpret_cast<const float4*>(rowp + ((q ^ qx) << 2));
        #pragma unroll
        for (int r = 0; r < 8; ++r) {
          acc[r*16+4*q+0] += xk[r] * w4.x;
          acc[r*16+4*q+1] += xk[r] * w4.y;
          acc[r*16+4*q+2] += xk[r] * w4.z;
          acc[r*16+4*q+3] += xk[r] * w4.w;
        }
      }
    }
  };

  stage(0);
  loadx(xc, 0);
  __syncthreads();                        // W1 phase0 ready

  #pragma unroll
  for (int c = 0; c < 8; ++c) {
    if (c < 7) loadx(xn, c + 1);          // prefetch next chunk's x early
    compute(xc, c);
    if ((c & 1) == 1 && c < 7) {          // phase boundary
      __syncthreads();                    // all waves done reading phase LDS
      stage((c >> 1) + 1);
      __syncthreads();                    // new W1 ready
    }
    if (c < 7) {
      #pragma unroll
      for (int r = 0; r < 8; ++r) xc[r] = xn[r];
    }
  }

  // two reduce-scatters (rows 0..3 in acc[0..63], rows 4..7 in acc[64..127])
  #pragma unroll
  for (int b = 32; b >= 1; b >>= 1) {
    bool hi = (lane & b) != 0;
    #pragma unroll
    for (int j = 0; j < b; ++j) {
      float sA = hi ? acc[j] : acc[b + j];
      float rA = __shfl_xor(sA, b);
      acc[j] = (hi ? acc[b + j] : acc[j]) + rA;
      float sB = hi ? acc[64 + j] : acc[64 + b + j];
      float rB = __shfl_xor(sB, b);
      acc[64 + j] = (hi ? acc[64 + b + j] : acc[64 + j]) + rB;
    }
  }
  int r = lane >> 4, cch = lane & 15;
  int row0 = rowbase + r, row1 = rowbase + 4 + r;
  if (row0 < n) h0b[(size_t)row0 * 16 + cch] = __float2bfloat16(acc[0]);
  if (row1 < n) h0b[(size_t)row1 * 16 + cch] = __float2bfloat16(acc[64]);
}

// ---------------------------------------------------------------------------
// K2: in-degree count
// ---------------------------------------------------------------------------
__global__ void k_deg(const int* __restrict__ edst, int* __restrict__ deg, int e) {
  int i = blockIdx.x * 256 + threadIdx.x;
  if (i < e) atomicAdd(&deg[edst[i]], 1);
}

// ---------------------------------------------------------------------------
// K3a/b/c: exclusive prefix scan of deg -> rowptr (+cursor); dinv
// ---------------------------------------------------------------------------
__global__ void k_scan_a(const int* __restrict__ deg, int* __restrict__ bsum, int n) {
  __shared__ int s[256];
  int i = blockIdx.x * 256 + threadIdx.x;
  s[threadIdx.x] = (i < n) ? deg[i] : 0;
  __syncthreads();
  for (int off = 128; off > 0; off >>= 1) {
    if (threadIdx.x < off) s[threadIdx.x] += s[threadIdx.x + off];
    __syncthreads();
  }
  if (threadIdx.x == 0) bsum[blockIdx.x] = s[0];
}

__global__ void k_scan_b(int* __restrict__ bsum, int nb) {
  int lane = threadIdx.x;   // 64 threads
  int carry = 0;
  for (int base = 0; base < nb; base += 64) {
    int idx = base + lane;
    int orig = (idx < nb) ? bsum[idx] : 0;
    int v = orig;
    #pragma unroll
    for (int off = 1; off < 64; off <<= 1) {
      int tv = __shfl_up(v, off);
      if (lane >= off) v += tv;
    }
    if (idx < nb) bsum[idx] = carry + v - orig;   // exclusive
    carry += __shfl(v, 63);
  }
}

__global__ void k_scan_c(const int* __restrict__ deg, const int* __restrict__ bsum,
                         int* __restrict__ rowptr, int* __restrict__ cursor,
                         float* __restrict__ dinv, int n) {
  __shared__ int s[256];
  int i = blockIdx.x * 256 + threadIdx.x;
  int v = (i < n) ? deg[i] : 0;
  s[threadIdx.x] = v;
  __syncthreads();
  for (int off = 1; off < 256; off <<= 1) {
    int tv = (threadIdx.x >= off) ? s[threadIdx.x - off] : 0;
    __syncthreads();
    s[threadIdx.x] += tv;
    __syncthreads();
  }
  int excl = s[threadIdx.x] - v + bsum[blockIdx.x];
  if (i < n) {
    rowptr[i] = excl;
    cursor[i] = excl;
    dinv[i] = rsqrtf((float)(v + 1));
    if (i == n - 1) rowptr[n] = excl + v;
  }
}

// ---------------------------------------------------------------------------
// K4: scatter edges into CSR
// ---------------------------------------------------------------------------
__global__ void k_scatter(const int* __restrict__ esrc, const int* __restrict__ edst,
                          int* __restrict__ cursor, int* __restrict__ csr, int e) {
  int i = blockIdx.x * 256 + threadIdx.x;
  if (i < e) {
    int d = edst[i];
    int pos = atomicAdd(&cursor[d], 1);
    csr[pos] = esrc[i];
  }
}

// ---------------------------------------------------------------------------
// K5: per-dst GCN aggregate + bias + relu, g = h@Wg (bf16 out), a_s/a_d dots.
// h0 is bf16 (gather bytes halved).
// ---------------------------------------------------------------------------
__global__ __launch_bounds__(256) void k_gcn(
    const unsigned short* __restrict__ h0b, const int* __restrict__ rowptr,
    const int* __restrict__ csr, const float* __restrict__ dinv,
    const float* __restrict__ b1, const float* __restrict__ Wg,
    const float* __restrict__ atts, const float* __restrict__ attd,
    __hip_bfloat16* __restrict__ gb, float* __restrict__ a_s,
    float* __restrict__ a_d, int n) {
  __shared__ float wgs[HID * HC];
  __shared__ float ats[HC], atd[HC];
  int t = threadIdx.x;
  for (int i = t; i < HID * HC; i += 256) wgs[i] = Wg[i];
  if (t < HC) { ats[t] = atts[t]; atd[t] = attd[t]; }
  __syncthreads();

  int lane = t & 63, w = t >> 6;
  int dst = blockIdx.x * 4 + w;
  if (dst >= n) return;
  int j = lane >> 4, c = lane & 15;
  int start = rowptr[dst], end = rowptr[dst + 1];
  float dd = dinv[dst];

  float acc = 0.f;
  for (int idx = start + j; idx < end; idx += 4) {
    int src = csr[idx];
    acc += bf2f(h0b[(size_t)src * 16 + c]) * dinv[src];
  }
  acc += __shfl_xor(acc, 16);
  acc += __shfl_xor(acc, 32);
  acc = acc * dd + bf2f(h0b[(size_t)dst * 16 + c]) * dd * dd;  // + self loop
  float hv = fmaxf(acc + b1[c], 0.f);

  float go = 0.f;
  #pragma unroll
  for (int k = 0; k < 16; ++k) {
    float hk = __shfl(hv, k);
    go += hk * wgs[k * HC + lane];
  }
  gb[(size_t)dst * HC + lane] = __float2bfloat16(go);

  float asv = go * ats[lane], adv = go * atd[lane];
  #pragma unroll
  for (int m = 1; m < 16; m <<= 1) {
    asv += __shfl_xor(asv, m);
    adv += __shfl_xor(adv, m);
  }
  if (c == 0) {
    a_s[(size_t)dst * 4 + j] = asv;
    a_d[(size_t)dst * 4 + j] = adv;
  }
}

// ---------------------------------------------------------------------------
// K6: per-dst GAT, SINGLE online-softmax edge sweep + classifier + log_softmax.
// One wave per dst. j=lane>>4 edge stripe, c=lane&15 (channels 4c..4c+3),
// head=c>>2. Branchless online update: corr=exp(m-mnew) rescale.
// g is bf16 (gather bytes halved).
// ---------------------------------------------------------------------------
__global__ __launch_bounds__(256) void k_gat(
    const unsigned short* __restrict__ gb, const int* __restrict__ rowptr,
    const int* __restrict__ csr, const float* __restrict__ a_s,
    const float* __restrict__ a_d, const float* __restrict__ bg,
    const float* __restrict__ Wo, const float* __restrict__ bo,
    float* __restrict__ out, int n) {
  __shared__ float wos[HC * NCLS];
  __shared__ float bgs[HC];
  __shared__ float bos[NCLS];
  int t = threadIdx.x;
  if (t < HC * NCLS) wos[t] = Wo[t];
  if (t < HC) bgs[t] = bg[t];
  if (t < NCLS) bos[t] = bo[t];
  __syncthreads();

  int lane = t & 63, w = t >> 6;
  int dst = blockIdx.x * 4 + w;
  if (dst >= n) return;
  int start = rowptr[dst], end = rowptr[dst + 1];
  int j = lane >> 4, c = lane & 15, h = c >> 2;

  float adh = a_d[(size_t)dst * 4 + h];
  float ash = a_s[(size_t)dst * 4 + h];

  float m = -1e30f, den = 0.f;
  float a0 = 0.f, a1 = 0.f, a2 = 0.f, a3 = 0.f;

  for (int idx = start + j; idx < end; idx += 4) {
    int src = csr[idx];
    float e = lrelu(a_s[(size_t)src * 4 + h] + adh);
    float mn = fmaxf(m, e);
    float corr = __expf(m - mn);          // 1 when no new max
    float p = __expf(e - mn);
    ushort4 u4 = *reinterpret_cast<const ushort4*>(gb + (size_t)src * HC + c * 4);
    den = den * corr + p;
    a0 = a0 * corr + p * bf2f(u4.x);
    a1 = a1 * corr + p * bf2f(u4.y);
    a2 = a2 * corr + p * bf2f(u4.z);
    a3 = a3 * corr + p * bf2f(u4.w);
    m = mn;
  }
  if (j == 0) {                            // self loop, counted once
    float e = lrelu(ash + adh);
    float mn = fmaxf(m, e);
    float corr = __expf(m - mn);
    float p = __expf(e - mn);
    ushort4 u4 = *reinterpret_cast<const ushort4*>(gb + (size_t)dst * HC + c * 4);
    den = den * corr + p;
    a0 = a0 * corr + p * bf2f(u4.x);
    a1 = a1 * corr + p * bf2f(u4.y);
    a2 = a2 * corr + p * bf2f(u4.z);
    a3 = a3 * corr + p * bf2f(u4.w);
    m = mn;
  }

  // merge the 4 j-stripes (lanes differing in bits 4,5)
  #pragma unroll
  for (int msk = 16; msk <= 32; msk <<= 1) {
    float m2 = __shfl_xor(m, msk);
    float d2 = __shfl_xor(den, msk);
    float b0 = __shfl_xor(a0, msk);
    float b1v = __shfl_xor(a1, msk);
    float b2 = __shfl_xor(a2, msk);
    float b3 = __shfl_xor(a3, msk);
    float M = fmaxf(m, m2);
    float c1 = __expf(m - M), c2 = __expf(m2 - M);
    den = den * c1 + d2 * c2;
    a0 = a0 * c1 + b0 * c2;
    a1 = a1 * c1 + b1v * c2;
    a2 = a2 * c1 + b2 * c2;
    a3 = a3 * c1 + b3 * c2;
    m = M;
  }
  den += 1e-16f;

  float o0 = a0 / den + bgs[c * 4 + 0];
  float o1 = a1 / den + bgs[c * 4 + 1];
  float o2 = a2 / den + bgs[c * 4 + 2];
  float o3 = a3 / den + bgs[c * 4 + 3];

  float p0 = 0.f, p1 = 0.f, p2 = 0.f;
  {
    int ch = c * 4;
    p0 += o0 * wos[(ch+0)*NCLS+0] + o1 * wos[(ch+1)*NCLS+0] + o2 * wos[(ch+2)*NCLS+0] + o3 * wos[(ch+3)*NCLS+0];
    p1 += o0 * wos[(ch+0)*NCLS+1] + o1 * wos[(ch+1)*NCLS+1] + o2 * wos[(ch+2)*NCLS+1] + o3 * wos[(ch+3)*NCLS+1];
    p2 += o0 * wos[(ch+0)*NCLS+2] + o1 * wos[(ch+1)*NCLS+2] + o2 * wos[(ch+2)*NCLS+2] + o3 * wos[(ch+3)*NCLS+2];
  }
  #pragma unroll
  for (int msk = 1; msk < 16; msk <<= 1) {
    p0 += __shfl_xor(p0, msk);
    p1 += __shfl_xor(p1, msk);
    p2 += __shfl_xor(p2, msk);
  }
  p0 += bos[0]; p1 += bos[1]; p2 += bos[2];
  float mx = fmaxf(p0, fmaxf(p1, p2));
  float ls = mx + logf(__expf(p0 - mx) + __expf(p1 - mx) + __expf(p2 - mx));
  if (lane == 0) {
    out[(size_t)dst * 3 + 0] = p0 - ls;
    out[(size_t)dst * 3 + 1] = p1 - ls;
    out[(size_t)dst * 3 + 2] = p2 - ls;
  }
}

// ---------------------------------------------------------------------------
extern "C" void kernel_launch(void* const* d_in, const int* in_sizes, int n_in,
                              void* d_out, int out_size, void* d_ws, size_t ws_size,
                              hipStream_t stream) {
  const float* x    = (const float*)d_in[0];
  const int*   ei   = (const int*)  d_in[1];
  const float* W1   = (const float*)d_in[2];
  const float* b1   = (const float*)d_in[3];
  const float* Wg   = (const float*)d_in[4];
  const float* atts = (const float*)d_in[5];
  const float* attd = (const float*)d_in[6];
  const float* bg   = (const float*)d_in[7];
  const float* Wo   = (const float*)d_in[8];
  const float* bo   = (const float*)d_in[9];
  float* out = (float*)d_out;

  const int n = in_sizes[0] / F_IN;
  const int e = in_sizes[1] / 2;
  const int* esrc = ei;
  const int* edst = ei + e;

  char* p = (char*)d_ws;
  auto alloc = [&](size_t bytes) { char* r = p; p += (bytes + 255) & ~(size_t)255; return r; };
  __hip_bfloat16* h0b = (__hip_bfloat16*)alloc((size_t)n * 16 * 2);
  int*   deg    = (int*)  alloc((size_t)n * 4);
  int*   cursor = (int*)  alloc((size_t)n * 4);
  float* dinv   = (float*)alloc((size_t)n * 4);
  int*   rowptr = (int*)  alloc((size_t)(n + 1) * 4);
  int*   bsum   = (int*)  alloc(4096);
  int*   csr    = (int*)  alloc((size_t)e * 4);
  __hip_bfloat16* gbuf = (__hip_bfloat16*)alloc((size_t)n * HC * 2);
  float* as_    = (float*)alloc((size_t)n * 4 * 4);
  float* ad_    = (float*)alloc((size_t)n * 4 * 4);

  int nzb = (n + 255) / 256;
  k_zero<<<nzb, 256, 0, stream>>>(deg, n);

  k_gemm1<<<(n + 31) / 32, 256, 0, stream>>>(x, W1, h0b, n);

  k_deg<<<(e + 255) / 256, 256, 0, stream>>>(edst, deg, e);

  int nb = (n + 255) / 256;
  k_scan_a<<<nb, 256, 0, stream>>>(deg, bsum, n);
  k_scan_b<<<1, 64, 0, stream>>>(bsum, nb);
  k_scan_c<<<nb, 256, 0, stream>>>(deg, bsum, rowptr, cursor, dinv, n);

  k_scatter<<<(e + 255) / 256, 256, 0, stream>>>(esrc, edst, cursor, csr, e);

  k_gcn<<<(n + 3) / 4, 256, 0, stream>>>((const unsigned short*)h0b, rowptr, csr,
                                         dinv, b1, Wg, atts, attd,
                                         gbuf, as_, ad_, n);

  k_gat<<<(n + 3) / 4, 256, 0, stream>>>((const unsigned short*)gbuf, rowptr, csr,
                                         as_, ad_, bg, Wo, bo, out, n);
}

// Round 7
// 542.194 us; speedup vs baseline: 2.5736x; 1.8095x over previous
//
#include <hip/hip_runtime.h>
#include <hip/hip_bf16.h>
#include <math.h>

#define F_IN   2000
#define HID    16
#define HEADS  4
#define CPH    16
#define HC     64
#define NCLS   3

__device__ __forceinline__ float lrelu(float x){ return x > 0.f ? x : 0.2f*x; }

__device__ __forceinline__ float comp4(const float4& v, int k){
  return k==0 ? v.x : k==1 ? v.y : k==2 ? v.z : v.w;
}

__device__ __forceinline__ float bf2f(unsigned short u){
  return __uint_as_float(((unsigned)u) << 16);
}

// ---------------------------------------------------------------------------
// K0: zero deg
// ---------------------------------------------------------------------------
__global__ void k_zero(int* __restrict__ deg, int n) {
  int i = blockIdx.x * 256 + threadIdx.x;
  if (i < n) deg[i] = 0;
}

// ---------------------------------------------------------------------------
// K1: h0 = x @ W1 -> bf16.  NO LDS, NO barriers.
// 256 thr = 4 waves x 4 rows. W1 (128KB) is L2-resident -- each lane loads
// its 4 W1 rows (4x float4 per kk) straight from L2 inside the kk loop;
// x read as float4 with explicit next-chunk prefetch (xc/xn ping-pong).
// Per chunk: 20 loads issued, then 256 FMAs (512 cyc) cover L2 latency.
// Latency hiding via free-running waves (no __syncthreads anywhere).
// ---------------------------------------------------------------------------
__global__ __launch_bounds__(256) void k_gemm1(const float* __restrict__ x,
                                               const float* __restrict__ W1,
                                               __hip_bfloat16* __restrict__ h0b,
                                               int n) {
  const int t    = threadIdx.x;
  const int lane = t & 63;
  const int wid  = t >> 6;               // 0..3
  const int rowbase = blockIdx.x * 16 + wid * 4;
  const float4* __restrict__ w1f4 = reinterpret_cast<const float4*>(W1);

  float acc[64];                         // acc[r*16+c]
  #pragma unroll
  for (int v = 0; v < 64; ++v) acc[v] = 0.f;

  float4 xc[4], xn[4];

  auto loadx = [&](float4* xv, int ci) {
    const int f4l = ci * 64 + lane;
    const bool kv = (f4l < 500);
    #pragma unroll
    for (int r = 0; r < 4; ++r) {
      int row = rowbase + r;
      xv[r] = (kv && row < n)
          ? *reinterpret_cast<const float4*>(x + (size_t)row * F_IN + f4l * 4)
          : make_float4(0.f, 0.f, 0.f, 0.f);
    }
  };

  loadx(xc, 0);

  for (int ci = 0; ci < 8; ++ci) {
    if (ci < 7) loadx(xn, ci + 1);        // prefetch next chunk's x
    const int f4l = ci * 64 + lane;
    const int kc = (f4l < 500) ? f4l : 0; // clamp: x already zeroed when invalid
    #pragma unroll
    for (int kk = 0; kk < 4; ++kk) {
      const int k = 4 * kc + kk;          // W1 row, <= 1999
      float4 w0 = w1f4[k * 4 + 0];
      float4 w1v = w1f4[k * 4 + 1];
      float4 w2 = w1f4[k * 4 + 2];
      float4 w3 = w1f4[k * 4 + 3];
      #pragma unroll
      for (int r = 0; r < 4; ++r) {
        float xk = comp4(xc[r], kk);
        acc[r*16+ 0] += xk * w0.x;  acc[r*16+ 1] += xk * w0.y;
        acc[r*16+ 2] += xk * w0.z;  acc[r*16+ 3] += xk * w0.w;
        acc[r*16+ 4] += xk * w1v.x; acc[r*16+ 5] += xk * w1v.y;
        acc[r*16+ 6] += xk * w1v.z; acc[r*16+ 7] += xk * w1v.w;
        acc[r*16+ 8] += xk * w2.x;  acc[r*16+ 9] += xk * w2.y;
        acc[r*16+10] += xk * w2.z;  acc[r*16+11] += xk * w2.w;
        acc[r*16+12] += xk * w3.x;  acc[r*16+13] += xk * w3.y;
        acc[r*16+14] += xk * w3.z;  acc[r*16+15] += xk * w3.w;
      }
    }
    if (ci < 7) {
      #pragma unroll
      for (int r = 0; r < 4; ++r) xc[r] = xn[r];
    }
  }

  // reduce-scatter across 64 lanes: final acc[0] = full sum for value v=lane,
  // lane layout (r=lane>>4, c=lane&15).
  #pragma unroll
  for (int b = 32; b >= 1; b >>= 1) {
    bool hi = (lane & b) != 0;
    #pragma unroll
    for (int j = 0; j < b; ++j) {
      float send = hi ? acc[j] : acc[b + j];
      float recv = __shfl_xor(send, b);
      acc[j] = (hi ? acc[b + j] : acc[j]) + recv;
    }
  }
  int r = lane >> 4, c = lane & 15;
  int row = rowbase + r;
  if (row < n) h0b[(size_t)row * 16 + c] = __float2bfloat16(acc[0]);
}

// ---------------------------------------------------------------------------
// K2: in-degree count
// ---------------------------------------------------------------------------
__global__ void k_deg(const int* __restrict__ edst, int* __restrict__ deg, int e) {
  int i = blockIdx.x * 256 + threadIdx.x;
  if (i < e) atomicAdd(&deg[edst[i]], 1);
}

// ---------------------------------------------------------------------------
// K3a/b/c: exclusive prefix scan of deg -> rowptr (+cursor); dinv
// ---------------------------------------------------------------------------
__global__ void k_scan_a(const int* __restrict__ deg, int* __restrict__ bsum, int n) {
  __shared__ int s[256];
  int i = blockIdx.x * 256 + threadIdx.x;
  s[threadIdx.x] = (i < n) ? deg[i] : 0;
  __syncthreads();
  for (int off = 128; off > 0; off >>= 1) {
    if (threadIdx.x < off) s[threadIdx.x] += s[threadIdx.x + off];
    __syncthreads();
  }
  if (threadIdx.x == 0) bsum[blockIdx.x] = s[0];
}

__global__ void k_scan_b(int* __restrict__ bsum, int nb) {
  int lane = threadIdx.x;   // 64 threads
  int carry = 0;
  for (int base = 0; base < nb; base += 64) {
    int idx = base + lane;
    int orig = (idx < nb) ? bsum[idx] : 0;
    int v = orig;
    #pragma unroll
    for (int off = 1; off < 64; off <<= 1) {
      int tv = __shfl_up(v, off);
      if (lane >= off) v += tv;
    }
    if (idx < nb) bsum[idx] = carry + v - orig;   // exclusive
    carry += __shfl(v, 63);
  }
}

__global__ void k_scan_c(const int* __restrict__ deg, const int* __restrict__ bsum,
                         int* __restrict__ rowptr, int* __restrict__ cursor,
                         float* __restrict__ dinv, int n) {
  __shared__ int s[256];
  int i = blockIdx.x * 256 + threadIdx.x;
  int v = (i < n) ? deg[i] : 0;
  s[threadIdx.x] = v;
  __syncthreads();
  for (int off = 1; off < 256; off <<= 1) {
    int tv = (threadIdx.x >= off) ? s[threadIdx.x - off] : 0;
    __syncthreads();
    s[threadIdx.x] += tv;
    __syncthreads();
  }
  int excl = s[threadIdx.x] - v + bsum[blockIdx.x];
  if (i < n) {
    rowptr[i] = excl;
    cursor[i] = excl;
    dinv[i] = rsqrtf((float)(v + 1));
    if (i == n - 1) rowptr[n] = excl + v;
  }
}

// ---------------------------------------------------------------------------
// K4: scatter edges into CSR
// ---------------------------------------------------------------------------
__global__ void k_scatter(const int* __restrict__ esrc, const int* __restrict__ edst,
                          int* __restrict__ cursor, int* __restrict__ csr, int e) {
  int i = blockIdx.x * 256 + threadIdx.x;
  if (i < e) {
    int d = edst[i];
    int pos = atomicAdd(&cursor[d], 1);
    csr[pos] = esrc[i];
  }
}

// ---------------------------------------------------------------------------
// K5: per-dst GCN aggregate + bias + relu, g = h@Wg (bf16 out), a_s/a_d dots.
// ---------------------------------------------------------------------------
__global__ __launch_bounds__(256) void k_gcn(
    const unsigned short* __restrict__ h0b, const int* __restrict__ rowptr,
    const int* __restrict__ csr, const float* __restrict__ dinv,
    const float* __restrict__ b1, const float* __restrict__ Wg,
    const float* __restrict__ atts, const float* __restrict__ attd,
    __hip_bfloat16* __restrict__ gb, float* __restrict__ a_s,
    float* __restrict__ a_d, int n) {
  __shared__ float wgs[HID * HC];
  __shared__ float ats[HC], atd[HC];
  int t = threadIdx.x;
  for (int i = t; i < HID * HC; i += 256) wgs[i] = Wg[i];
  if (t < HC) { ats[t] = atts[t]; atd[t] = attd[t]; }
  __syncthreads();

  int lane = t & 63, w = t >> 6;
  int dst = blockIdx.x * 4 + w;
  if (dst >= n) return;
  int j = lane >> 4, c = lane & 15;
  int start = rowptr[dst], end = rowptr[dst + 1];
  float dd = dinv[dst];

  float acc = 0.f;
  for (int idx = start + j; idx < end; idx += 4) {
    int src = csr[idx];
    acc += bf2f(h0b[(size_t)src * 16 + c]) * dinv[src];
  }
  acc += __shfl_xor(acc, 16);
  acc += __shfl_xor(acc, 32);
  acc = acc * dd + bf2f(h0b[(size_t)dst * 16 + c]) * dd * dd;  // + self loop
  float hv = fmaxf(acc + b1[c], 0.f);

  float go = 0.f;
  #pragma unroll
  for (int k = 0; k < 16; ++k) {
    float hk = __shfl(hv, k);
    go += hk * wgs[k * HC + lane];
  }
  gb[(size_t)dst * HC + lane] = __float2bfloat16(go);

  float asv = go * ats[lane], adv = go * atd[lane];
  #pragma unroll
  for (int m = 1; m < 16; m <<= 1) {
    asv += __shfl_xor(asv, m);
    adv += __shfl_xor(adv, m);
  }
  if (c == 0) {
    a_s[(size_t)dst * 4 + j] = asv;
    a_d[(size_t)dst * 4 + j] = adv;
  }
}

// ---------------------------------------------------------------------------
// K6: per-dst GAT, SINGLE online-softmax edge sweep + classifier + log_softmax.
// ---------------------------------------------------------------------------
__global__ __launch_bounds__(256) void k_gat(
    const unsigned short* __restrict__ gb, const int* __restrict__ rowptr,
    const int* __restrict__ csr, const float* __restrict__ a_s,
    const float* __restrict__ a_d, const float* __restrict__ bg,
    const float* __restrict__ Wo, const float* __restrict__ bo,
    float* __restrict__ out, int n) {
  __shared__ float wos[HC * NCLS];
  __shared__ float bgs[HC];
  __shared__ float bos[NCLS];
  int t = threadIdx.x;
  if (t < HC * NCLS) wos[t] = Wo[t];
  if (t < HC) bgs[t] = bg[t];
  if (t < NCLS) bos[t] = bo[t];
  __syncthreads();

  int lane = t & 63, w = t >> 6;
  int dst = blockIdx.x * 4 + w;
  if (dst >= n) return;
  int start = rowptr[dst], end = rowptr[dst + 1];
  int j = lane >> 4, c = lane & 15, h = c >> 2;

  float adh = a_d[(size_t)dst * 4 + h];
  float ash = a_s[(size_t)dst * 4 + h];

  float m = -1e30f, den = 0.f;
  float a0 = 0.f, a1 = 0.f, a2 = 0.f, a3 = 0.f;

  for (int idx = start + j; idx < end; idx += 4) {
    int src = csr[idx];
    float e = lrelu(a_s[(size_t)src * 4 + h] + adh);
    float mn = fmaxf(m, e);
    float corr = __expf(m - mn);          // 1 when no new max
    float p = __expf(e - mn);
    ushort4 u4 = *reinterpret_cast<const ushort4*>(gb + (size_t)src * HC + c * 4);
    den = den * corr + p;
    a0 = a0 * corr + p * bf2f(u4.x);
    a1 = a1 * corr + p * bf2f(u4.y);
    a2 = a2 * corr + p * bf2f(u4.z);
    a3 = a3 * corr + p * bf2f(u4.w);
    m = mn;
  }
  if (j == 0) {                            // self loop, counted once
    float e = lrelu(ash + adh);
    float mn = fmaxf(m, e);
    float corr = __expf(m - mn);
    float p = __expf(e - mn);
    ushort4 u4 = *reinterpret_cast<const ushort4*>(gb + (size_t)dst * HC + c * 4);
    den = den * corr + p;
    a0 = a0 * corr + p * bf2f(u4.x);
    a1 = a1 * corr + p * bf2f(u4.y);
    a2 = a2 * corr + p * bf2f(u4.z);
    a3 = a3 * corr + p * bf2f(u4.w);
    m = mn;
  }

  // merge the 4 j-stripes (lanes differing in bits 4,5)
  #pragma unroll
  for (int msk = 16; msk <= 32; msk <<= 1) {
    float m2 = __shfl_xor(m, msk);
    float d2 = __shfl_xor(den, msk);
    float b0 = __shfl_xor(a0, msk);
    float b1v = __shfl_xor(a1, msk);
    float b2 = __shfl_xor(a2, msk);
    float b3 = __shfl_xor(a3, msk);
    float M = fmaxf(m, m2);
    float c1 = __expf(m - M), c2 = __expf(m2 - M);
    den = den * c1 + d2 * c2;
    a0 = a0 * c1 + b0 * c2;
    a1 = a1 * c1 + b1v * c2;
    a2 = a2 * c1 + b2 * c2;
    a3 = a3 * c1 + b3 * c2;
    m = M;
  }
  den += 1e-16f;

  float o0 = a0 / den + bgs[c * 4 + 0];
  float o1 = a1 / den + bgs[c * 4 + 1];
  float o2 = a2 / den + bgs[c * 4 + 2];
  float o3 = a3 / den + bgs[c * 4 + 3];

  float p0 = 0.f, p1 = 0.f, p2 = 0.f;
  {
    int ch = c * 4;
    p0 += o0 * wos[(ch+0)*NCLS+0] + o1 * wos[(ch+1)*NCLS+0] + o2 * wos[(ch+2)*NCLS+0] + o3 * wos[(ch+3)*NCLS+0];
    p1 += o0 * wos[(ch+0)*NCLS+1] + o1 * wos[(ch+1)*NCLS+1] + o2 * wos[(ch+2)*NCLS+1] + o3 * wos[(ch+3)*NCLS+1];
    p2 += o0 * wos[(ch+0)*NCLS+2] + o1 * wos[(ch+1)*NCLS+2] + o2 * wos[(ch+2)*NCLS+2] + o3 * wos[(ch+3)*NCLS+2];
  }
  #pragma unroll
  for (int msk = 1; msk < 16; msk <<= 1) {
    p0 += __shfl_xor(p0, msk);
    p1 += __shfl_xor(p1, msk);
    p2 += __shfl_xor(p2, msk);
  }
  p0 += bos[0]; p1 += bos[1]; p2 += bos[2];
  float mx = fmaxf(p0, fmaxf(p1, p2));
  float ls = mx + logf(__expf(p0 - mx) + __expf(p1 - mx) + __expf(p2 - mx));
  if (lane == 0) {
    out[(size_t)dst * 3 + 0] = p0 - ls;
    out[(size_t)dst * 3 + 1] = p1 - ls;
    out[(size_t)dst * 3 + 2] = p2 - ls;
  }
}

// ---------------------------------------------------------------------------
extern "C" void kernel_launch(void* const* d_in, const int* in_sizes, int n_in,
                              void* d_out, int out_size, void* d_ws, size_t ws_size,
                              hipStream_t stream) {
  const float* x    = (const float*)d_in[0];
  const int*   ei   = (const int*)  d_in[1];
  const float* W1   = (const float*)d_in[2];
  const float* b1   = (const float*)d_in[3];
  const float* Wg   = (const float*)d_in[4];
  const float* atts = (const float*)d_in[5];
  const float* attd = (const float*)d_in[6];
  const float* bg   = (const float*)d_in[7];
  const float* Wo   = (const float*)d_in[8];
  const float* bo   = (const float*)d_in[9];
  float* out = (float*)d_out;

  const int n = in_sizes[0] / F_IN;
  const int e = in_sizes[1] / 2;
  const int* esrc = ei;
  const int* edst = ei + e;

  char* p = (char*)d_ws;
  auto alloc = [&](size_t bytes) { char* r = p; p += (bytes + 255) & ~(size_t)255; return r; };
  __hip_bfloat16* h0b = (__hip_bfloat16*)alloc((size_t)n * 16 * 2);
  int*   deg    = (int*)  alloc((size_t)n * 4);
  int*   cursor = (int*)  alloc((size_t)n * 4);
  float* dinv   = (float*)alloc((size_t)n * 4);
  int*   rowptr = (int*)  alloc((size_t)(n + 1) * 4);
  int*   bsum   = (int*)  alloc(4096);
  int*   csr    = (int*)  alloc((size_t)e * 4);
  __hip_bfloat16* gbuf = (__hip_bfloat16*)alloc((size_t)n * HC * 2);
  float* as_    = (float*)alloc((size_t)n * 4 * 4);
  float* ad_    = (float*)alloc((size_t)n * 4 * 4);

  int nzb = (n + 255) / 256;
  k_zero<<<nzb, 256, 0, stream>>>(deg, n);

  k_gemm1<<<(n + 15) / 16, 256, 0, stream>>>(x, W1, h0b, n);

  k_deg<<<(e + 255) / 256, 256, 0, stream>>>(edst, deg, e);

  int nb = (n + 255) / 256;
  k_scan_a<<<nb, 256, 0, stream>>>(deg, bsum, n);
  k_scan_b<<<1, 64, 0, stream>>>(bsum, nb);
  k_scan_c<<<nb, 256, 0, stream>>>(deg, bsum, rowptr, cursor, dinv, n);

  k_scatter<<<(e + 255) / 256, 256, 0, stream>>>(esrc, edst, cursor, csr, e);

  k_gcn<<<(n + 3) / 4, 256, 0, stream>>>((const unsigned short*)h0b, rowptr, csr,
                                         dinv, b1, Wg, atts, attd,
                                         gbuf, as_, ad_, n);

  k_gat<<<(n + 3) / 4, 256, 0, stream>>>((const unsigned short*)gbuf, rowptr, csr,
                                         as_, ad_, bg, Wo, bo, out, n);
}

// Round 8
// 490.548 us; speedup vs baseline: 2.8445x; 1.1053x over previous
//
#include <hip/hip_runtime.h>
#include <hip/hip_bf16.h>
#include <math.h>

#define F_IN   2000
#define HID    16
#define HEADS  4
#define CPH    16
#define HC     64
#define NCLS   3

__device__ __forceinline__ float lrelu(float x){ return x > 0.f ? x : 0.2f*x; }

__device__ __forceinline__ float comp4(const float4& v, int k){
  return k==0 ? v.x : k==1 ? v.y : k==2 ? v.z : v.w;
}

__device__ __forceinline__ float bf2f(unsigned short u){
  return __uint_as_float(((unsigned)u) << 16);
}

// ---------------------------------------------------------------------------
// K0: zero deg
// ---------------------------------------------------------------------------
__global__ void k_zero(int* __restrict__ deg, int n) {
  int i = blockIdx.x * 256 + threadIdx.x;
  if (i < n) deg[i] = 0;
}

// ---------------------------------------------------------------------------
// K1: h0 = x @ W1 -> bf16   [n,2000]@[2000,16]
// 256 thr = 4 waves x 4 rows. W1 in LDS (32KB, 4 phases of 500 rows),
// REG-STAGED: coalesced linear global reads -> ds_write to quad-rotated
// layout slot(k,q)=k*16+((q+(k>>2))&3)*4 (write conflict-free; read ~R5
// level). Rows 500..511 zero-filled (avoid 0*NaN on tail lanes).
// x: depth-2 prefetch ring xs[3] (fully unrolled -> static reg indexing);
// 1024 cyc FMA cover >= ~900 cyc HBM latency. Stage-loads for phase p+1
// issue at start of phase p compute (issue-early / write-late).
// ---------------------------------------------------------------------------
__global__ __launch_bounds__(256) void k_gemm1(const float* __restrict__ x,
                                               const float* __restrict__ W1,
                                               __hip_bfloat16* __restrict__ h0b,
                                               int n) {
  __shared__ float w1s[8192];            // 512 rows x 16 floats (rotated quads)
  const int t    = threadIdx.x;
  const int lane = t & 63;
  const int wid  = t >> 6;               // 0..3
  const int rowbase = blockIdx.x * 16 + wid * 4;

  float acc[64];                         // acc[r*16+c]
  #pragma unroll
  for (int v = 0; v < 64; ++v) acc[v] = 0.f;

  float4 sreg[8];                        // staging regs: 8 float4 / thread
  float4 xs[3][4];                       // x prefetch ring (static idx, unrolled)

  auto stage_load = [&](int p) {         // linear, coalesced global reads
    const size_t kbase = (size_t)p * 500 * 16;
    #pragma unroll
    for (int b = 0; b < 8; ++b) {
      int f = t + 256 * b;               // float4 index 0..2047 (valid <2000)
      int fc = (f < 2000) ? f : 1999;
      sreg[b] = *reinterpret_cast<const float4*>(W1 + kbase + (size_t)fc * 4);
    }
  };
  auto stage_write = [&]() {             // quad-rotated LDS layout
    #pragma unroll
    for (int b = 0; b < 8; ++b) {
      int f = t + 256 * b;
      int k = f >> 2, q = f & 3;
      int qs = (q + (k >> 2)) & 3;
      float4 v = (f < 2000) ? sreg[b] : make_float4(0.f, 0.f, 0.f, 0.f);
      *reinterpret_cast<float4*>(w1s + k * 16 + qs * 4) = v;   // k<512 in-bounds
    }
  };
  auto loadxs = [&](float4* xv, int ci) {
    const int f4l = (ci & 1) * 64 + lane;
    const bool kv = (f4l < 125);
    const int base = (ci >> 1) * 500 + f4l * 4;
    #pragma unroll
    for (int r = 0; r < 4; ++r) {
      xv[r] = kv ? *reinterpret_cast<const float4*>(x + (size_t)(rowbase + r) * F_IN + base)
                 : make_float4(0.f, 0.f, 0.f, 0.f);
    }
  };
  auto compute = [&](const float4* xv, int ci) {
    const int f4l = (ci & 1) * 64 + lane;
    #pragma unroll
    for (int kk = 0; kk < 4; ++kk) {
      const int rs = 4 * f4l + kk;       // local W1 row slot (<512)
      const float* rowp = w1s + rs * 16;
      float xk0 = comp4(xv[0], kk), xk1 = comp4(xv[1], kk);
      float xk2 = comp4(xv[2], kk), xk3 = comp4(xv[3], kk);
      #pragma unroll
      for (int q = 0; q < 4; ++q) {
        const int qs = (q + f4l) & 3;    // rotated slot of logical quad q
        float4 w4 = *reinterpret_cast<const float4*>(rowp + (qs << 2));
        acc[0*16+4*q+0] += xk0 * w4.x; acc[0*16+4*q+1] += xk0 * w4.y;
        acc[0*16+4*q+2] += xk0 * w4.z; acc[0*16+4*q+3] += xk0 * w4.w;
        acc[1*16+4*q+0] += xk1 * w4.x; acc[1*16+4*q+1] += xk1 * w4.y;
        acc[1*16+4*q+2] += xk1 * w4.z; acc[1*16+4*q+3] += xk1 * w4.w;
        acc[2*16+4*q+0] += xk2 * w4.x; acc[2*16+4*q+1] += xk2 * w4.y;
        acc[2*16+4*q+2] += xk2 * w4.z; acc[2*16+4*q+3] += xk2 * w4.w;
        acc[3*16+4*q+0] += xk3 * w4.x; acc[3*16+4*q+1] += xk3 * w4.y;
        acc[3*16+4*q+2] += xk3 * w4.z; acc[3*16+4*q+3] += xk3 * w4.w;
      }
    }
  };

  // prologue: stage phase0, prime x depth-2
  stage_load(0);
  loadxs(xs[0], 0);
  loadxs(xs[1], 1);
  stage_write();                          // waits sreg loads (vmcnt)
  __syncthreads();                        // phase0 visible

  #pragma unroll
  for (int ci = 0; ci < 8; ++ci) {
    if ((ci & 1) == 0 && ci < 6) stage_load((ci >> 1) + 1);  // issue early
    if (ci < 6) loadxs(xs[(ci + 2) % 3], ci + 2);            // depth-2 x
    compute(xs[ci % 3], ci);
    if ((ci & 1) == 1 && ci < 7) {
      __syncthreads();                    // all waves done reading phase
      stage_write();                      // write-late
      __syncthreads();                    // new phase visible
    }
  }

  // reduce-scatter across 64 lanes: final acc[0] = full sum for value v=lane,
  // lane layout (r=lane>>4, c=lane&15).
  #pragma unroll
  for (int b = 32; b >= 1; b >>= 1) {
    bool hi = (lane & b) != 0;
    #pragma unroll
    for (int j = 0; j < b; ++j) {
      float send = hi ? acc[j] : acc[b + j];
      float recv = __shfl_xor(send, b);
      acc[j] = (hi ? acc[b + j] : acc[j]) + recv;
    }
  }
  int r = lane >> 4, c = lane & 15;
  int row = rowbase + r;
  if (row < n) h0b[(size_t)row * 16 + c] = __float2bfloat16(acc[0]);
}

// ---------------------------------------------------------------------------
// K2: in-degree count
// ---------------------------------------------------------------------------
__global__ void k_deg(const int* __restrict__ edst, int* __restrict__ deg, int e) {
  int i = blockIdx.x * 256 + threadIdx.x;
  if (i < e) atomicAdd(&deg[edst[i]], 1);
}

// ---------------------------------------------------------------------------
// K3a/b/c: exclusive prefix scan of deg -> rowptr (+cursor); dinv
// ---------------------------------------------------------------------------
__global__ void k_scan_a(const int* __restrict__ deg, int* __restrict__ bsum, int n) {
  __shared__ int s[256];
  int i = blockIdx.x * 256 + threadIdx.x;
  s[threadIdx.x] = (i < n) ? deg[i] : 0;
  __syncthreads();
  for (int off = 128; off > 0; off >>= 1) {
    if (threadIdx.x < off) s[threadIdx.x] += s[threadIdx.x + off];
    __syncthreads();
  }
  if (threadIdx.x == 0) bsum[blockIdx.x] = s[0];
}

__global__ void k_scan_b(int* __restrict__ bsum, int nb) {
  int lane = threadIdx.x;   // 64 threads
  int carry = 0;
  for (int base = 0; base < nb; base += 64) {
    int idx = base + lane;
    int orig = (idx < nb) ? bsum[idx] : 0;
    int v = orig;
    #pragma unroll
    for (int off = 1; off < 64; off <<= 1) {
      int tv = __shfl_up(v, off);
      if (lane >= off) v += tv;
    }
    if (idx < nb) bsum[idx] = carry + v - orig;   // exclusive
    carry += __shfl(v, 63);
  }
}

__global__ void k_scan_c(const int* __restrict__ deg, const int* __restrict__ bsum,
                         int* __restrict__ rowptr, int* __restrict__ cursor,
                         float* __restrict__ dinv, int n) {
  __shared__ int s[256];
  int i = blockIdx.x * 256 + threadIdx.x;
  int v = (i < n) ? deg[i] : 0;
  s[threadIdx.x] = v;
  __syncthreads();
  for (int off = 1; off < 256; off <<= 1) {
    int tv = (threadIdx.x >= off) ? s[threadIdx.x - off] : 0;
    __syncthreads();
    s[threadIdx.x] += tv;
    __syncthreads();
  }
  int excl = s[threadIdx.x] - v + bsum[blockIdx.x];
  if (i < n) {
    rowptr[i] = excl;
    cursor[i] = excl;
    dinv[i] = rsqrtf((float)(v + 1));
    if (i == n - 1) rowptr[n] = excl + v;
  }
}

// ---------------------------------------------------------------------------
// K4: scatter edges into CSR
// ---------------------------------------------------------------------------
__global__ void k_scatter(const int* __restrict__ esrc, const int* __restrict__ edst,
                          int* __restrict__ cursor, int* __restrict__ csr, int e) {
  int i = blockIdx.x * 256 + threadIdx.x;
  if (i < e) {
    int d = edst[i];
    int pos = atomicAdd(&cursor[d], 1);
    csr[pos] = esrc[i];
  }
}

// ---------------------------------------------------------------------------
// K5: per-dst GCN aggregate + bias + relu, g = h@Wg (bf16 out), a_s/a_d dots.
// ---------------------------------------------------------------------------
__global__ __launch_bounds__(256) void k_gcn(
    const unsigned short* __restrict__ h0b, const int* __restrict__ rowptr,
    const int* __restrict__ csr, const float* __restrict__ dinv,
    const float* __restrict__ b1, const float* __restrict__ Wg,
    const float* __restrict__ atts, const float* __restrict__ attd,
    __hip_bfloat16* __restrict__ gb, float* __restrict__ a_s,
    float* __restrict__ a_d, int n) {
  __shared__ float wgs[HID * HC];
  __shared__ float ats[HC], atd[HC];
  int t = threadIdx.x;
  for (int i = t; i < HID * HC; i += 256) wgs[i] = Wg[i];
  if (t < HC) { ats[t] = atts[t]; atd[t] = attd[t]; }
  __syncthreads();

  int lane = t & 63, w = t >> 6;
  int dst = blockIdx.x * 4 + w;
  if (dst >= n) return;
  int j = lane >> 4, c = lane & 15;
  int start = rowptr[dst], end = rowptr[dst + 1];
  float dd = dinv[dst];

  float acc = 0.f;
  for (int idx = start + j; idx < end; idx += 4) {
    int src = csr[idx];
    acc += bf2f(h0b[(size_t)src * 16 + c]) * dinv[src];
  }
  acc += __shfl_xor(acc, 16);
  acc += __shfl_xor(acc, 32);
  acc = acc * dd + bf2f(h0b[(size_t)dst * 16 + c]) * dd * dd;  // + self loop
  float hv = fmaxf(acc + b1[c], 0.f);

  float go = 0.f;
  #pragma unroll
  for (int k = 0; k < 16; ++k) {
    float hk = __shfl(hv, k);
    go += hk * wgs[k * HC + lane];
  }
  gb[(size_t)dst * HC + lane] = __float2bfloat16(go);

  float asv = go * ats[lane], adv = go * atd[lane];
  #pragma unroll
  for (int m = 1; m < 16; m <<= 1) {
    asv += __shfl_xor(asv, m);
    adv += __shfl_xor(adv, m);
  }
  if (c == 0) {
    a_s[(size_t)dst * 4 + j] = asv;
    a_d[(size_t)dst * 4 + j] = adv;
  }
}

// ---------------------------------------------------------------------------
// K6: per-dst GAT, SINGLE online-softmax edge sweep + classifier + log_softmax.
// ---------------------------------------------------------------------------
__global__ __launch_bounds__(256) void k_gat(
    const unsigned short* __restrict__ gb, const int* __restrict__ rowptr,
    const int* __restrict__ csr, const float* __restrict__ a_s,
    const float* __restrict__ a_d, const float* __restrict__ bg,
    const float* __restrict__ Wo, const float* __restrict__ bo,
    float* __restrict__ out, int n) {
  __shared__ float wos[HC * NCLS];
  __shared__ float bgs[HC];
  __shared__ float bos[NCLS];
  int t = threadIdx.x;
  if (t < HC * NCLS) wos[t] = Wo[t];
  if (t < HC) bgs[t] = bg[t];
  if (t < NCLS) bos[t] = bo[t];
  __syncthreads();

  int lane = t & 63, w = t >> 6;
  int dst = blockIdx.x * 4 + w;
  if (dst >= n) return;
  int start = rowptr[dst], end = rowptr[dst + 1];
  int j = lane >> 4, c = lane & 15, h = c >> 2;

  float adh = a_d[(size_t)dst * 4 + h];
  float ash = a_s[(size_t)dst * 4 + h];

  float m = -1e30f, den = 0.f;
  float a0 = 0.f, a1 = 0.f, a2 = 0.f, a3 = 0.f;

  for (int idx = start + j; idx < end; idx += 4) {
    int src = csr[idx];
    float e = lrelu(a_s[(size_t)src * 4 + h] + adh);
    float mn = fmaxf(m, e);
    float corr = __expf(m - mn);          // 1 when no new max
    float p = __expf(e - mn);
    ushort4 u4 = *reinterpret_cast<const ushort4*>(gb + (size_t)src * HC + c * 4);
    den = den * corr + p;
    a0 = a0 * corr + p * bf2f(u4.x);
    a1 = a1 * corr + p * bf2f(u4.y);
    a2 = a2 * corr + p * bf2f(u4.z);
    a3 = a3 * corr + p * bf2f(u4.w);
    m = mn;
  }
  if (j == 0) {                            // self loop, counted once
    float e = lrelu(ash + adh);
    float mn = fmaxf(m, e);
    float corr = __expf(m - mn);
    float p = __expf(e - mn);
    ushort4 u4 = *reinterpret_cast<const ushort4*>(gb + (size_t)dst * HC + c * 4);
    den = den * corr + p;
    a0 = a0 * corr + p * bf2f(u4.x);
    a1 = a1 * corr + p * bf2f(u4.y);
    a2 = a2 * corr + p * bf2f(u4.z);
    a3 = a3 * corr + p * bf2f(u4.w);
    m = mn;
  }

  // merge the 4 j-stripes (lanes differing in bits 4,5)
  #pragma unroll
  for (int msk = 16; msk <= 32; msk <<= 1) {
    float m2 = __shfl_xor(m, msk);
    float d2 = __shfl_xor(den, msk);
    float b0 = __shfl_xor(a0, msk);
    float b1v = __shfl_xor(a1, msk);
    float b2 = __shfl_xor(a2, msk);
    float b3 = __shfl_xor(a3, msk);
    float M = fmaxf(m, m2);
    float c1 = __expf(m - M), c2 = __expf(m2 - M);
    den = den * c1 + d2 * c2;
    a0 = a0 * c1 + b0 * c2;
    a1 = a1 * c1 + b1v * c2;
    a2 = a2 * c1 + b2 * c2;
    a3 = a3 * c1 + b3 * c2;
    m = M;
  }
  den += 1e-16f;

  float o0 = a0 / den + bgs[c * 4 + 0];
  float o1 = a1 / den + bgs[c * 4 + 1];
  float o2 = a2 / den + bgs[c * 4 + 2];
  float o3 = a3 / den + bgs[c * 4 + 3];

  float p0 = 0.f, p1 = 0.f, p2 = 0.f;
  {
    int ch = c * 4;
    p0 += o0 * wos[(ch+0)*NCLS+0] + o1 * wos[(ch+1)*NCLS+0] + o2 * wos[(ch+2)*NCLS+0] + o3 * wos[(ch+3)*NCLS+0];
    p1 += o0 * wos[(ch+0)*NCLS+1] + o1 * wos[(ch+1)*NCLS+1] + o2 * wos[(ch+2)*NCLS+1] + o3 * wos[(ch+3)*NCLS+1];
    p2 += o0 * wos[(ch+0)*NCLS+2] + o1 * wos[(ch+1)*NCLS+2] + o2 * wos[(ch+2)*NCLS+2] + o3 * wos[(ch+3)*NCLS+2];
  }
  #pragma unroll
  for (int msk = 1; msk < 16; msk <<= 1) {
    p0 += __shfl_xor(p0, msk);
    p1 += __shfl_xor(p1, msk);
    p2 += __shfl_xor(p2, msk);
  }
  p0 += bos[0]; p1 += bos[1]; p2 += bos[2];
  float mx = fmaxf(p0, fmaxf(p1, p2));
  float ls = mx + logf(__expf(p0 - mx) + __expf(p1 - mx) + __expf(p2 - mx));
  if (lane == 0) {
    out[(size_t)dst * 3 + 0] = p0 - ls;
    out[(size_t)dst * 3 + 1] = p1 - ls;
    out[(size_t)dst * 3 + 2] = p2 - ls;
  }
}

// ---------------------------------------------------------------------------
extern "C" void kernel_launch(void* const* d_in, const int* in_sizes, int n_in,
                              void* d_out, int out_size, void* d_ws, size_t ws_size,
                              hipStream_t stream) {
  const float* x    = (const float*)d_in[0];
  const int*   ei   = (const int*)  d_in[1];
  const float* W1   = (const float*)d_in[2];
  const float* b1   = (const float*)d_in[3];
  const float* Wg   = (const float*)d_in[4];
  const float* atts = (const float*)d_in[5];
  const float* attd = (const float*)d_in[6];
  const float* bg   = (const float*)d_in[7];
  const float* Wo   = (const float*)d_in[8];
  const float* bo   = (const float*)d_in[9];
  float* out = (float*)d_out;

  const int n = in_sizes[0] / F_IN;
  const int e = in_sizes[1] / 2;
  const int* esrc = ei;
  const int* edst = ei + e;

  char* p = (char*)d_ws;
  auto alloc = [&](size_t bytes) { char* r = p; p += (bytes + 255) & ~(size_t)255; return r; };
  __hip_bfloat16* h0b = (__hip_bfloat16*)alloc((size_t)n * 16 * 2);
  int*   deg    = (int*)  alloc((size_t)n * 4);
  int*   cursor = (int*)  alloc((size_t)n * 4);
  float* dinv   = (float*)alloc((size_t)n * 4);
  int*   rowptr = (int*)  alloc((size_t)(n + 1) * 4);
  int*   bsum   = (int*)  alloc(4096);
  int*   csr    = (int*)  alloc((size_t)e * 4);
  __hip_bfloat16* gbuf = (__hip_bfloat16*)alloc((size_t)n * HC * 2);
  float* as_    = (float*)alloc((size_t)n * 4 * 4);
  float* ad_    = (float*)alloc((size_t)n * 4 * 4);

  int nzb = (n + 255) / 256;
  k_zero<<<nzb, 256, 0, stream>>>(deg, n);

  k_gemm1<<<(n + 15) / 16, 256, 0, stream>>>(x, W1, h0b, n);

  k_deg<<<(e + 255) / 256, 256, 0, stream>>>(edst, deg, e);

  int nb = (n + 255) / 256;
  k_scan_a<<<nb, 256, 0, stream>>>(deg, bsum, n);
  k_scan_b<<<1, 64, 0, stream>>>(bsum, nb);
  k_scan_c<<<nb, 256, 0, stream>>>(deg, bsum, rowptr, cursor, dinv, n);

  k_scatter<<<(e + 255) / 256, 256, 0, stream>>>(esrc, edst, cursor, csr, e);

  k_gcn<<<(n + 3) / 4, 256, 0, stream>>>((const unsigned short*)h0b, rowptr, csr,
                                         dinv, b1, Wg, atts, attd,
                                         gbuf, as_, ad_, n);

  k_gat<<<(n + 3) / 4, 256, 0, stream>>>((const unsigned short*)gbuf, rowptr, csr,
                                         as_, ad_, bg, Wo, bo, out, n);
}

// Round 9
// 437.152 us; speedup vs baseline: 3.1920x; 1.1221x over previous
//
#include <hip/hip_runtime.h>
#include <hip/hip_bf16.h>
#include <math.h>

#define F_IN   2000
#define HID    16
#define HEADS  4
#define CPH    16
#define HC     64
#define NCLS   3

__device__ __forceinline__ float lrelu(float x){ return x > 0.f ? x : 0.2f*x; }

__device__ __forceinline__ float comp4(const float4& v, int k){
  return k==0 ? v.x : k==1 ? v.y : k==2 ? v.z : v.w;
}

__device__ __forceinline__ float bf2f(unsigned short u){
  return __uint_as_float(((unsigned)u) << 16);
}

// ---------------------------------------------------------------------------
// K0: zero deg (must precede fused deg-count)
// ---------------------------------------------------------------------------
__global__ void k_zero(int* __restrict__ deg, int n) {
  int i = blockIdx.x * 256 + threadIdx.x;
  if (i < n) deg[i] = 0;
}

// ---------------------------------------------------------------------------
// K1 (fused): blocks [0, ngemm) run the R4-exact gemm (h0 = x@W1 -> bf16,
// global_load_lds staging w/ pre-swizzled source, 137us measured @R5);
// blocks [ngemm, ngemm+ndeg) run the in-degree atomic count. The gemm is
// latency-bound (22% occ, 18% HBM) so deg blocks ride in its idle slots.
// ---------------------------------------------------------------------------
__global__ __launch_bounds__(256) void k_gemm_deg(const float* __restrict__ x,
                                                  const float* __restrict__ W1,
                                                  __hip_bfloat16* __restrict__ h0b,
                                                  int n, int ngemm,
                                                  const int* __restrict__ edst,
                                                  int* __restrict__ deg, int e) {
  __shared__ float w1s[8192];            // 512 rows x 16 floats (swizzled)
  if ((int)blockIdx.x >= ngemm) {        // ---- deg role ----
    int i = (blockIdx.x - ngemm) * 256 + threadIdx.x;
    if (i < e) atomicAdd(&deg[edst[i]], 1);
    return;
  }
  // ---- gemm role (R4-exact) ----
  const int t    = threadIdx.x;
  const int lane = t & 63;
  const int wid  = t >> 6;               // 0..3
  const int rowbase = blockIdx.x * 16 + wid * 4;

  float acc[64];                         // acc[r*16 + c]
  #pragma unroll
  for (int v = 0; v < 64; ++v) acc[v] = 0.f;

  for (int phase = 0; phase < 4; ++phase) {
    const int kbase = phase * 500;
    __syncthreads();
    #pragma unroll
    for (int k = 0; k < 8; ++k) {
      const int slotbase = (wid * 8 + k) * 64;      // wave-uniform
      const int slot = slotbase + lane;
      const int row_slot = slot >> 2;
      const int r = row_slot ^ ((row_slot >> 4) & 1);
      const int q = (slot & 3) ^ ((row_slot >> 2) & 3);
      int rg = kbase + r;
      if (rg > 1999) rg = 1999;                     // clamp; junk slots unread
      __builtin_amdgcn_global_load_lds(
          (const __attribute__((address_space(1))) void*)(W1 + (size_t)rg * 16 + q * 4),
          (__attribute__((address_space(3))) void*)(w1s + (size_t)slotbase * 4),
          16, 0, 0);
    }
    __syncthreads();                                // drains vmcnt -> LDS ready

    #pragma unroll
    for (int i = 0; i < 2; ++i) {
      int f4l = i * 64 + lane;            // local float4-of-K index, <125 valid
      if (f4l < 125) {
        float4 xv[4];
        #pragma unroll
        for (int r = 0; r < 4; ++r) {
          int row = rowbase + r;
          xv[r] = (row < n)
              ? *reinterpret_cast<const float4*>(
                    x + (size_t)row * F_IN + kbase + f4l * 4)
              : make_float4(0.f, 0.f, 0.f, 0.f);
        }
        const int qx = f4l & 3;
        const int xb = (f4l >> 2) & 1;
        #pragma unroll
        for (int kk = 0; kk < 4; ++kk) {
          const int rs = (4 * f4l + kk) ^ xb;       // swizzled row slot
          const float* rowp = w1s + rs * 16;
          float xk0 = comp4(xv[0], kk), xk1 = comp4(xv[1], kk);
          float xk2 = comp4(xv[2], kk), xk3 = comp4(xv[3], kk);
          #pragma unroll
          for (int q = 0; q < 4; ++q) {
            float4 w4 = *reinterpret_cast<const float4*>(rowp + ((q ^ qx) << 2));
            acc[0*16+4*q+0] += xk0 * w4.x; acc[0*16+4*q+1] += xk0 * w4.y;
            acc[0*16+4*q+2] += xk0 * w4.z; acc[0*16+4*q+3] += xk0 * w4.w;
            acc[1*16+4*q+0] += xk1 * w4.x; acc[1*16+4*q+1] += xk1 * w4.y;
            acc[1*16+4*q+2] += xk1 * w4.z; acc[1*16+4*q+3] += xk1 * w4.w;
            acc[2*16+4*q+0] += xk2 * w4.x; acc[2*16+4*q+1] += xk2 * w4.y;
            acc[2*16+4*q+2] += xk2 * w4.z; acc[2*16+4*q+3] += xk2 * w4.w;
            acc[3*16+4*q+0] += xk3 * w4.x; acc[3*16+4*q+1] += xk3 * w4.y;
            acc[3*16+4*q+2] += xk3 * w4.z; acc[3*16+4*q+3] += xk3 * w4.w;
          }
        }
      }
    }
  }

  // reduce-scatter across 64 lanes: final acc[0] = full sum for value v=lane,
  // lane layout (r=lane>>4, c=lane&15).
  #pragma unroll
  for (int b = 32; b >= 1; b >>= 1) {
    bool hi = (lane & b) != 0;
    #pragma unroll
    for (int j = 0; j < b; ++j) {
      float send = hi ? acc[j] : acc[b + j];
      float recv = __shfl_xor(send, b);
      acc[j] = (hi ? acc[b + j] : acc[j]) + recv;
    }
  }
  int r = lane >> 4, c = lane & 15;
  int row = rowbase + r;
  if (row < n) h0b[(size_t)row * 16 + c] = __float2bfloat16(acc[0]);
}

// ---------------------------------------------------------------------------
// K3a/b/c: exclusive prefix scan of deg -> rowptr (+cursor); dinv
// ---------------------------------------------------------------------------
__global__ void k_scan_a(const int* __restrict__ deg, int* __restrict__ bsum, int n) {
  __shared__ int s[256];
  int i = blockIdx.x * 256 + threadIdx.x;
  s[threadIdx.x] = (i < n) ? deg[i] : 0;
  __syncthreads();
  for (int off = 128; off > 0; off >>= 1) {
    if (threadIdx.x < off) s[threadIdx.x] += s[threadIdx.x + off];
    __syncthreads();
  }
  if (threadIdx.x == 0) bsum[blockIdx.x] = s[0];
}

__global__ void k_scan_b(int* __restrict__ bsum, int nb) {
  int lane = threadIdx.x;   // 64 threads
  int carry = 0;
  for (int base = 0; base < nb; base += 64) {
    int idx = base + lane;
    int orig = (idx < nb) ? bsum[idx] : 0;
    int v = orig;
    #pragma unroll
    for (int off = 1; off < 64; off <<= 1) {
      int tv = __shfl_up(v, off);
      if (lane >= off) v += tv;
    }
    if (idx < nb) bsum[idx] = carry + v - orig;   // exclusive
    carry += __shfl(v, 63);
  }
}

__global__ void k_scan_c(const int* __restrict__ deg, const int* __restrict__ bsum,
                         int* __restrict__ rowptr, int* __restrict__ cursor,
                         float* __restrict__ dinv, int n) {
  __shared__ int s[256];
  int i = blockIdx.x * 256 + threadIdx.x;
  int v = (i < n) ? deg[i] : 0;
  s[threadIdx.x] = v;
  __syncthreads();
  for (int off = 1; off < 256; off <<= 1) {
    int tv = (threadIdx.x >= off) ? s[threadIdx.x - off] : 0;
    __syncthreads();
    s[threadIdx.x] += tv;
    __syncthreads();
  }
  int excl = s[threadIdx.x] - v + bsum[blockIdx.x];
  if (i < n) {
    rowptr[i] = excl;
    cursor[i] = excl;
    dinv[i] = rsqrtf((float)(v + 1));
    if (i == n - 1) rowptr[n] = excl + v;
  }
}

// ---------------------------------------------------------------------------
// K4: scatter edges into CSR
// ---------------------------------------------------------------------------
__global__ void k_scatter(const int* __restrict__ esrc, const int* __restrict__ edst,
                          int* __restrict__ cursor, int* __restrict__ csr, int e) {
  int i = blockIdx.x * 256 + threadIdx.x;
  if (i < e) {
    int d = edst[i];
    int pos = atomicAdd(&cursor[d], 1);
    csr[pos] = esrc[i];
  }
}

// ---------------------------------------------------------------------------
// K5: per-dst GCN aggregate + bias + relu, g = h@Wg (bf16 out), a_s/a_d dots.
// ---------------------------------------------------------------------------
__global__ __launch_bounds__(256) void k_gcn(
    const unsigned short* __restrict__ h0b, const int* __restrict__ rowptr,
    const int* __restrict__ csr, const float* __restrict__ dinv,
    const float* __restrict__ b1, const float* __restrict__ Wg,
    const float* __restrict__ atts, const float* __restrict__ attd,
    __hip_bfloat16* __restrict__ gb, float* __restrict__ a_s,
    float* __restrict__ a_d, int n) {
  __shared__ float wgs[HID * HC];
  __shared__ float ats[HC], atd[HC];
  int t = threadIdx.x;
  for (int i = t; i < HID * HC; i += 256) wgs[i] = Wg[i];
  if (t < HC) { ats[t] = atts[t]; atd[t] = attd[t]; }
  __syncthreads();

  int lane = t & 63, w = t >> 6;
  int dst = blockIdx.x * 4 + w;
  if (dst >= n) return;
  int j = lane >> 4, c = lane & 15;
  int start = rowptr[dst], end = rowptr[dst + 1];
  float dd = dinv[dst];

  float acc = 0.f;
  for (int idx = start + j; idx < end; idx += 4) {
    int src = csr[idx];
    acc += bf2f(h0b[(size_t)src * 16 + c]) * dinv[src];
  }
  acc += __shfl_xor(acc, 16);
  acc += __shfl_xor(acc, 32);
  acc = acc * dd + bf2f(h0b[(size_t)dst * 16 + c]) * dd * dd;  // + self loop
  float hv = fmaxf(acc + b1[c], 0.f);

  float go = 0.f;
  #pragma unroll
  for (int k = 0; k < 16; ++k) {
    float hk = __shfl(hv, k);
    go += hk * wgs[k * HC + lane];
  }
  gb[(size_t)dst * HC + lane] = __float2bfloat16(go);

  float asv = go * ats[lane], adv = go * atd[lane];
  #pragma unroll
  for (int m = 1; m < 16; m <<= 1) {
    asv += __shfl_xor(asv, m);
    adv += __shfl_xor(adv, m);
  }
  if (c == 0) {
    a_s[(size_t)dst * 4 + j] = asv;
    a_d[(size_t)dst * 4 + j] = adv;
  }
}

// ---------------------------------------------------------------------------
// K6: per-dst GAT, SINGLE online-softmax edge sweep + classifier + log_softmax.
// ---------------------------------------------------------------------------
__global__ __launch_bounds__(256) void k_gat(
    const unsigned short* __restrict__ gb, const int* __restrict__ rowptr,
    const int* __restrict__ csr, const float* __restrict__ a_s,
    const float* __restrict__ a_d, const float* __restrict__ bg,
    const float* __restrict__ Wo, const float* __restrict__ bo,
    float* __restrict__ out, int n) {
  __shared__ float wos[HC * NCLS];
  __shared__ float bgs[HC];
  __shared__ float bos[NCLS];
  int t = threadIdx.x;
  if (t < HC * NCLS) wos[t] = Wo[t];
  if (t < HC) bgs[t] = bg[t];
  if (t < NCLS) bos[t] = bo[t];
  __syncthreads();

  int lane = t & 63, w = t >> 6;
  int dst = blockIdx.x * 4 + w;
  if (dst >= n) return;
  int start = rowptr[dst], end = rowptr[dst + 1];
  int j = lane >> 4, c = lane & 15, h = c >> 2;

  float adh = a_d[(size_t)dst * 4 + h];
  float ash = a_s[(size_t)dst * 4 + h];

  float m = -1e30f, den = 0.f;
  float a0 = 0.f, a1 = 0.f, a2 = 0.f, a3 = 0.f;

  for (int idx = start + j; idx < end; idx += 4) {
    int src = csr[idx];
    float e = lrelu(a_s[(size_t)src * 4 + h] + adh);
    float mn = fmaxf(m, e);
    float corr = __expf(m - mn);          // 1 when no new max
    float p = __expf(e - mn);
    ushort4 u4 = *reinterpret_cast<const ushort4*>(gb + (size_t)src * HC + c * 4);
    den = den * corr + p;
    a0 = a0 * corr + p * bf2f(u4.x);
    a1 = a1 * corr + p * bf2f(u4.y);
    a2 = a2 * corr + p * bf2f(u4.z);
    a3 = a3 * corr + p * bf2f(u4.w);
    m = mn;
  }
  if (j == 0) {                            // self loop, counted once
    float e = lrelu(ash + adh);
    float mn = fmaxf(m, e);
    float corr = __expf(m - mn);
    float p = __expf(e - mn);
    ushort4 u4 = *reinterpret_cast<const ushort4*>(gb + (size_t)dst * HC + c * 4);
    den = den * corr + p;
    a0 = a0 * corr + p * bf2f(u4.x);
    a1 = a1 * corr + p * bf2f(u4.y);
    a2 = a2 * corr + p * bf2f(u4.z);
    a3 = a3 * corr + p * bf2f(u4.w);
    m = mn;
  }

  // merge the 4 j-stripes (lanes differing in bits 4,5)
  #pragma unroll
  for (int msk = 16; msk <= 32; msk <<= 1) {
    float m2 = __shfl_xor(m, msk);
    float d2 = __shfl_xor(den, msk);
    float b0 = __shfl_xor(a0, msk);
    float b1v = __shfl_xor(a1, msk);
    float b2 = __shfl_xor(a2, msk);
    float b3 = __shfl_xor(a3, msk);
    float M = fmaxf(m, m2);
    float c1 = __expf(m - M), c2 = __expf(m2 - M);
    den = den * c1 + d2 * c2;
    a0 = a0 * c1 + b0 * c2;
    a1 = a1 * c1 + b1v * c2;
    a2 = a2 * c1 + b2 * c2;
    a3 = a3 * c1 + b3 * c2;
    m = M;
  }
  den += 1e-16f;

  float o0 = a0 / den + bgs[c * 4 + 0];
  float o1 = a1 / den + bgs[c * 4 + 1];
  float o2 = a2 / den + bgs[c * 4 + 2];
  float o3 = a3 / den + bgs[c * 4 + 3];

  float p0 = 0.f, p1 = 0.f, p2 = 0.f;
  {
    int ch = c * 4;
    p0 += o0 * wos[(ch+0)*NCLS+0] + o1 * wos[(ch+1)*NCLS+0] + o2 * wos[(ch+2)*NCLS+0] + o3 * wos[(ch+3)*NCLS+0];
    p1 += o0 * wos[(ch+0)*NCLS+1] + o1 * wos[(ch+1)*NCLS+1] + o2 * wos[(ch+2)*NCLS+1] + o3 * wos[(ch+3)*NCLS+1];
    p2 += o0 * wos[(ch+0)*NCLS+2] + o1 * wos[(ch+1)*NCLS+2] + o2 * wos[(ch+2)*NCLS+2] + o3 * wos[(ch+3)*NCLS+2];
  }
  #pragma unroll
  for (int msk = 1; msk < 16; msk <<= 1) {
    p0 += __shfl_xor(p0, msk);
    p1 += __shfl_xor(p1, msk);
    p2 += __shfl_xor(p2, msk);
  }
  p0 += bos[0]; p1 += bos[1]; p2 += bos[2];
  float mx = fmaxf(p0, fmaxf(p1, p2));
  float ls = mx + logf(__expf(p0 - mx) + __expf(p1 - mx) + __expf(p2 - mx));
  if (lane == 0) {
    out[(size_t)dst * 3 + 0] = p0 - ls;
    out[(size_t)dst * 3 + 1] = p1 - ls;
    out[(size_t)dst * 3 + 2] = p2 - ls;
  }
}

// ---------------------------------------------------------------------------
extern "C" void kernel_launch(void* const* d_in, const int* in_sizes, int n_in,
                              void* d_out, int out_size, void* d_ws, size_t ws_size,
                              hipStream_t stream) {
  const float* x    = (const float*)d_in[0];
  const int*   ei   = (const int*)  d_in[1];
  const float* W1   = (const float*)d_in[2];
  const float* b1   = (const float*)d_in[3];
  const float* Wg   = (const float*)d_in[4];
  const float* atts = (const float*)d_in[5];
  const float* attd = (const float*)d_in[6];
  const float* bg   = (const float*)d_in[7];
  const float* Wo   = (const float*)d_in[8];
  const float* bo   = (const float*)d_in[9];
  float* out = (float*)d_out;

  const int n = in_sizes[0] / F_IN;
  const int e = in_sizes[1] / 2;
  const int* esrc = ei;
  const int* edst = ei + e;

  char* p = (char*)d_ws;
  auto alloc = [&](size_t bytes) { char* r = p; p += (bytes + 255) & ~(size_t)255; return r; };
  __hip_bfloat16* h0b = (__hip_bfloat16*)alloc((size_t)n * 16 * 2);
  int*   deg    = (int*)  alloc((size_t)n * 4);
  int*   cursor = (int*)  alloc((size_t)n * 4);
  float* dinv   = (float*)alloc((size_t)n * 4);
  int*   rowptr = (int*)  alloc((size_t)(n + 1) * 4);
  int*   bsum   = (int*)  alloc(4096);
  int*   csr    = (int*)  alloc((size_t)e * 4);
  __hip_bfloat16* gbuf = (__hip_bfloat16*)alloc((size_t)n * HC * 2);
  float* as_    = (float*)alloc((size_t)n * 4 * 4);
  float* ad_    = (float*)alloc((size_t)n * 4 * 4);

  int nzb = (n + 255) / 256;
  k_zero<<<nzb, 256, 0, stream>>>(deg, n);

  const int ngemm = (n + 15) / 16;
  const int ndeg  = (e + 255) / 256;
  k_gemm_deg<<<ngemm + ndeg, 256, 0, stream>>>(x, W1, h0b, n, ngemm, edst, deg, e);

  int nb = (n + 255) / 256;
  k_scan_a<<<nb, 256, 0, stream>>>(deg, bsum, n);
  k_scan_b<<<1, 64, 0, stream>>>(bsum, nb);
  k_scan_c<<<nb, 256, 0, stream>>>(deg, bsum, rowptr, cursor, dinv, n);

  k_scatter<<<(e + 255) / 256, 256, 0, stream>>>(esrc, edst, cursor, csr, e);

  k_gcn<<<(n + 3) / 4, 256, 0, stream>>>((const unsigned short*)h0b, rowptr, csr,
                                         dinv, b1, Wg, atts, attd,
                                         gbuf, as_, ad_, n);

  k_gat<<<(n + 3) / 4, 256, 0, stream>>>((const unsigned short*)gbuf, rowptr, csr,
                                         as_, ad_, bg, Wo, bo, out, n);
}